// Round 2
// baseline (3873.401 us; speedup 1.0000x reference)
//
#include <hip/hip_runtime.h>
#include <hip/hip_bf16.h>

#define NN 50000

// ---------- helpers ----------
__device__ __forceinline__ float bf_lo(unsigned int p) {
    union { unsigned int u; float f; } c; c.u = p << 16; return c.f;
}
__device__ __forceinline__ float bf_hi(unsigned int p) {
    union { unsigned int u; float f; } c; c.u = p & 0xffff0000u; return c.f;
}
__device__ __forceinline__ unsigned short bfbits(float f) {
    __hip_bfloat16 h = __float2bfloat16(f);   // RNE
    union { __hip_bfloat16 b; unsigned short s; } c; c.b = h; return c.s;
}
__device__ __forceinline__ unsigned int pack_bf(float a, float b) {
    return (unsigned int)bfbits(a) | ((unsigned int)bfbits(b) << 16);
}

// ---------- degree ----------
__global__ void deg_kernel(const int* __restrict__ dst, float* __restrict__ deg, int E) {
    int e = blockIdx.x * blockDim.x + threadIdx.x;
    if (e < E) atomicAdd(&deg[dst[e]], 1.0f);
}
__global__ void inv_deg_kernel(float* __restrict__ deg, int n) {
    int i = blockIdx.x * blockDim.x + threadIdx.x;
    if (i < n) deg[i] = 1.0f / fmaxf(deg[i], 1.0f);
}

// ---------- scatter-add (mean aggregation numerator), 4 channels / thread ----------
__global__ void scatter_f32(const int* __restrict__ src, const int* __restrict__ dst,
                            const float* __restrict__ h, float* __restrict__ agg,
                            int E) {
    int tid = blockIdx.x * blockDim.x + threadIdx.x;
    int e = tid >> 5;          // 32 threads/edge * 4ch = 128 ch
    if (e >= E) return;
    int c = (tid & 31) << 2;
    int s = src[e], d = dst[e];
    float4 v = *(const float4*)(h + (size_t)s * 128 + c);
    float* ap = agg + (size_t)d * 128 + c;
    atomicAdd(ap + 0, v.x);
    atomicAdd(ap + 1, v.y);
    atomicAdd(ap + 2, v.z);
    atomicAdd(ap + 3, v.w);
}

// ---------- fused (agg*invd)@wn^T + x@wr^T + b  [+ relu] ----------
// Weights read from fp32 global (coalesced float2), converted to bf16 pairs,
// staged in LDS transposed with +1-pad stride: both the transposed staging
// write and the compute read are bank-conflict-free. Features/accumulators
// stay fp32 (only weight rounding -> err ~1e-3 << 2% threshold).
template <int C_IN, int C_OUT, bool RELU>
__global__ __launch_bounds__(C_OUT) void sage_gemm(
    const float* __restrict__ agg, const float* __restrict__ xr,
    const float* __restrict__ invd,
    const float* __restrict__ wn, const float* __restrict__ wr,
    const float* __restrict__ bias,
    float* __restrict__ out, int n_nodes) {
    constexpr int KK = C_IN / 2;       // packed k-pairs
    constexpr int LDW = C_OUT + 1;     // pad to break bank conflicts
    constexpr int NPB = 32;            // nodes per block

    __shared__ unsigned int wn_s[KK * LDW];
    __shared__ unsigned int wr_s[KK * LDW];
    __shared__ float fa[2][C_IN];
    __shared__ float fx[2][C_IN];

    const int j = threadIdx.x;
    for (int idx = j; idx < C_OUT * KK; idx += C_OUT) {
        int row = idx / KK;
        int kk = idx - row * KK;
        float2 wv = *(const float2*)(wn + (size_t)row * C_IN + 2 * kk); // coalesced
        float2 rv = *(const float2*)(wr + (size_t)row * C_IN + 2 * kk);
        wn_s[kk * LDW + row] = pack_bf(wv.x, wv.y);  // conflict-free (stride 129)
        wr_s[kk * LDW + row] = pack_bf(rv.x, rv.y);
    }
    float bj = bias[j];
    __syncthreads();

    int base = blockIdx.x * NPB;
    for (int p = 0; p < NPB; p += 2) {
        int n0 = base + p;
        // stage features for node pair
        for (int idx = j; idx < 2 * C_IN; idx += C_OUT) {
            int w = idx / C_IN;
            int k = idx - w * C_IN;
            int n = n0 + w;
            float a = 0.f, xv = 0.f;
            if (n < n_nodes) {
                float s = invd[n];
                a = agg[(size_t)n * C_IN + k] * s;
                xv = xr[(size_t)n * C_IN + k];
            }
            fa[w][k] = a;
            fx[w][k] = xv;
        }
        __syncthreads();

        float acc0 = bj, acc1 = bj;
#pragma unroll 8
        for (int kk = 0; kk < KK; kk++) {
            unsigned int wp = wn_s[kk * LDW + j];
            unsigned int rp = wr_s[kk * LDW + j];
            float w0 = bf_lo(wp), w1 = bf_hi(wp);
            float r0 = bf_lo(rp), r1 = bf_hi(rp);
            acc0 += fa[0][2 * kk] * w0 + fa[0][2 * kk + 1] * w1 +
                    fx[0][2 * kk] * r0 + fx[0][2 * kk + 1] * r1;
            acc1 += fa[1][2 * kk] * w0 + fa[1][2 * kk + 1] * w1 +
                    fx[1][2 * kk] * r0 + fx[1][2 * kk + 1] * r1;
        }
        if (RELU) { acc0 = fmaxf(acc0, 0.f); acc1 = fmaxf(acc1, 0.f); }
        if (n0 < n_nodes)     out[(size_t)n0 * C_OUT + j] = acc0;
        if (n0 + 1 < n_nodes) out[(size_t)(n0 + 1) * C_OUT + j] = acc1;
        __syncthreads();
    }
}

extern "C" void kernel_launch(void* const* d_in, const int* in_sizes, int n_in,
                              void* d_out, int out_size, void* d_ws, size_t ws_size,
                              hipStream_t stream) {
    const float* x  = (const float*)d_in[0];
    const int* ei   = (const int*)d_in[1];
    const float* w1n = (const float*)d_in[2];
    const float* w1r = (const float*)d_in[3];
    const float* b1  = (const float*)d_in[4];
    const float* w2n = (const float*)d_in[5];
    const float* w2r = (const float*)d_in[6];
    const float* b2  = (const float*)d_in[7];
    const float* w3n = (const float*)d_in[8];
    const float* w3r = (const float*)d_in[9];
    const float* b3  = (const float*)d_in[10];
    float* out = (float*)d_out;

    const int E = in_sizes[1] / 2;
    const int* src = ei;
    const int* dst = ei + E;

    char* ws = (char*)d_ws;
    float* agg = (float*)ws;                              // 50000*128*4 = 25.6 MB
    float* h1  = (float*)(ws + 25600000);                 // 25.6 MB
    float* h2  = (float*)(ws + 51200000);                 // 25.6 MB
    float* deg = (float*)(ws + 76800000);                 // 200 KB

    const size_t aggBytes = (size_t)NN * 128 * sizeof(float);
    const int scatterBlocks = (E * 32 + 255) / 256;
    const int gemmBlocks = (NN + 31) / 32;

    // degree (reused for all 3 layers)
    hipMemsetAsync(deg, 0, NN * sizeof(float), stream);
    deg_kernel<<<(E + 255) / 256, 256, 0, stream>>>(dst, deg, E);
    inv_deg_kernel<<<(NN + 255) / 256, 256, 0, stream>>>(deg, NN);

    // layer 1: x -> h1, relu
    hipMemsetAsync(agg, 0, aggBytes, stream);
    scatter_f32<<<scatterBlocks, 256, 0, stream>>>(src, dst, x, agg, E);
    sage_gemm<128, 128, true>
        <<<gemmBlocks, 128, 0, stream>>>(agg, x, deg, w1n, w1r, b1, h1, NN);

    // layer 2: h1 -> h2, relu
    hipMemsetAsync(agg, 0, aggBytes, stream);
    scatter_f32<<<scatterBlocks, 256, 0, stream>>>(src, dst, h1, agg, E);
    sage_gemm<128, 128, true>
        <<<gemmBlocks, 128, 0, stream>>>(agg, h1, deg, w2n, w2r, b2, h2, NN);

    // layer 3: h2 -> out (fp32), no relu
    hipMemsetAsync(agg, 0, aggBytes, stream);
    scatter_f32<<<scatterBlocks, 256, 0, stream>>>(src, dst, h2, agg, E);
    sage_gemm<128, 64, false>
        <<<gemmBlocks, 64, 0, stream>>>(agg, h2, deg, w3n, w3r, b3, out, NN);
}

// Round 3
// 1097.616 us; speedup vs baseline: 3.5289x; 3.5289x over previous
//
#include <hip/hip_runtime.h>
#include <hip/hip_bf16.h>

#define NN 50000

// ---------- helpers ----------
__device__ __forceinline__ float bf_lo(unsigned int p) {
    union { unsigned int u; float f; } c; c.u = p << 16; return c.f;
}
__device__ __forceinline__ float bf_hi(unsigned int p) {
    union { unsigned int u; float f; } c; c.u = p & 0xffff0000u; return c.f;
}
__device__ __forceinline__ unsigned short bfbits(float f) {
    __hip_bfloat16 h = __float2bfloat16(f);   // RNE
    union { __hip_bfloat16 b; unsigned short s; } c; c.b = h; return c.s;
}
__device__ __forceinline__ unsigned int pack_bf(float a, float b) {
    return (unsigned int)bfbits(a) | ((unsigned int)bfbits(b) << 16);
}

// ---------- CSR build ----------
__global__ void count_kernel(const int* __restrict__ dst, int* __restrict__ cnt, int E) {
    int e = blockIdx.x * blockDim.x + threadIdx.x;
    if (e < E) atomicAdd(&cnt[dst[e]], 1);
}

// Single-block exclusive scan over cnt -> rowptr; also emits invd and inits
// cursor (cursor aliases cnt: each element is read before overwritten by the
// same thread).
__global__ __launch_bounds__(1024) void scan_kernel(
    int* __restrict__ cnt_cursor, int* __restrict__ rowptr,
    float* __restrict__ invd, int n) {
    __shared__ int part[1024];
    const int t = threadIdx.x;
    const int chunk = (n + 1023) / 1024;
    const int beg = t * chunk;
    const int end = min(beg + chunk, n);
    int s = 0;
    for (int i = beg; i < end; i++) s += cnt_cursor[i];
    part[t] = s;
    __syncthreads();
    for (int off = 1; off < 1024; off <<= 1) {
        int v = (t >= off) ? part[t - off] : 0;
        __syncthreads();
        part[t] += v;
        __syncthreads();
    }
    int run = (t == 0) ? 0 : part[t - 1];
    for (int i = beg; i < end; i++) {
        int c = cnt_cursor[i];
        rowptr[i] = run;
        cnt_cursor[i] = run;                 // cursor init
        invd[i] = 1.0f / fmaxf((float)c, 1.0f);
        run += c;
    }
    if (t == 1023) rowptr[n] = run;          // == E
}

__global__ void fill_kernel(const int* __restrict__ src, const int* __restrict__ dst,
                            int* __restrict__ cursor, int* __restrict__ col, int E) {
    int e = blockIdx.x * blockDim.x + threadIdx.x;
    if (e < E) {
        int p = atomicAdd(&cursor[dst[e]], 1);
        col[p] = src[e];
    }
}

// ---------- CSR gather-sum (mean numerator): 32 lanes x float4 per node ----------
__global__ __launch_bounds__(256) void gather_kernel(
    const int* __restrict__ rowptr, const int* __restrict__ col,
    const float* __restrict__ h, float* __restrict__ agg, int n_nodes) {
    int tid = blockIdx.x * blockDim.x + threadIdx.x;
    int n = tid >> 5;
    if (n >= n_nodes) return;
    int c = (tid & 31) << 2;
    int beg = rowptr[n], end = rowptr[n + 1];
    float4 acc = {0.f, 0.f, 0.f, 0.f};
    int i = beg;
    for (; i + 1 < end; i += 2) {
        int s0 = col[i], s1 = col[i + 1];
        float4 v0 = *(const float4*)(h + (size_t)s0 * 128 + c);
        float4 v1 = *(const float4*)(h + (size_t)s1 * 128 + c);
        acc.x += v0.x + v1.x; acc.y += v0.y + v1.y;
        acc.z += v0.z + v1.z; acc.w += v0.w + v1.w;
    }
    if (i < end) {
        int s = col[i];
        float4 v = *(const float4*)(h + (size_t)s * 128 + c);
        acc.x += v.x; acc.y += v.y; acc.z += v.z; acc.w += v.w;
    }
    *(float4*)(agg + (size_t)n * 128 + c) = acc;
}

// ---------- fused (agg*invd)@wn^T + x@wr^T + b  [+ relu] ----------
template <int C_IN, int C_OUT, bool RELU>
__global__ __launch_bounds__(C_OUT) void sage_gemm(
    const float* __restrict__ agg, const float* __restrict__ xr,
    const float* __restrict__ invd,
    const float* __restrict__ wn, const float* __restrict__ wr,
    const float* __restrict__ bias,
    float* __restrict__ out, int n_nodes) {
    constexpr int KK = C_IN / 2;       // packed k-pairs
    constexpr int LDW = C_OUT + 1;     // pad to break bank conflicts
    constexpr int NPB = 32;            // nodes per block

    __shared__ unsigned int wn_s[KK * LDW];
    __shared__ unsigned int wr_s[KK * LDW];
    __shared__ float fa[2][C_IN];
    __shared__ float fx[2][C_IN];

    const int j = threadIdx.x;
    for (int idx = j; idx < C_OUT * KK; idx += C_OUT) {
        int row = idx / KK;
        int kk = idx - row * KK;
        float2 wv = *(const float2*)(wn + (size_t)row * C_IN + 2 * kk);
        float2 rv = *(const float2*)(wr + (size_t)row * C_IN + 2 * kk);
        wn_s[kk * LDW + row] = pack_bf(wv.x, wv.y);
        wr_s[kk * LDW + row] = pack_bf(rv.x, rv.y);
    }
    float bj = bias[j];
    __syncthreads();

    int base = blockIdx.x * NPB;
    for (int p = 0; p < NPB; p += 2) {
        int n0 = base + p;
        for (int idx = j; idx < 2 * C_IN; idx += C_OUT) {
            int w = idx / C_IN;
            int k = idx - w * C_IN;
            int n = n0 + w;
            float a = 0.f, xv = 0.f;
            if (n < n_nodes) {
                float s = invd[n];
                a = agg[(size_t)n * C_IN + k] * s;
                xv = xr[(size_t)n * C_IN + k];
            }
            fa[w][k] = a;
            fx[w][k] = xv;
        }
        __syncthreads();

        float acc0 = bj, acc1 = bj;
#pragma unroll 8
        for (int kk = 0; kk < KK; kk++) {
            unsigned int wp = wn_s[kk * LDW + j];
            unsigned int rp = wr_s[kk * LDW + j];
            float w0 = bf_lo(wp), w1 = bf_hi(wp);
            float r0 = bf_lo(rp), r1 = bf_hi(rp);
            acc0 += fa[0][2 * kk] * w0 + fa[0][2 * kk + 1] * w1 +
                    fx[0][2 * kk] * r0 + fx[0][2 * kk + 1] * r1;
            acc1 += fa[1][2 * kk] * w0 + fa[1][2 * kk + 1] * w1 +
                    fx[1][2 * kk] * r0 + fx[1][2 * kk + 1] * r1;
        }
        if (RELU) { acc0 = fmaxf(acc0, 0.f); acc1 = fmaxf(acc1, 0.f); }
        if (n0 < n_nodes)     out[(size_t)n0 * C_OUT + j] = acc0;
        if (n0 + 1 < n_nodes) out[(size_t)(n0 + 1) * C_OUT + j] = acc1;
        __syncthreads();
    }
}

extern "C" void kernel_launch(void* const* d_in, const int* in_sizes, int n_in,
                              void* d_out, int out_size, void* d_ws, size_t ws_size,
                              hipStream_t stream) {
    const float* x  = (const float*)d_in[0];
    const int* ei   = (const int*)d_in[1];
    const float* w1n = (const float*)d_in[2];
    const float* w1r = (const float*)d_in[3];
    const float* b1  = (const float*)d_in[4];
    const float* w2n = (const float*)d_in[5];
    const float* w2r = (const float*)d_in[6];
    const float* b2  = (const float*)d_in[7];
    const float* w3n = (const float*)d_in[8];
    const float* w3r = (const float*)d_in[9];
    const float* b3  = (const float*)d_in[10];
    float* out = (float*)d_out;

    const int E = in_sizes[1] / 2;
    const int* src = ei;
    const int* dst = ei + E;

    // workspace layout
    char* ws = (char*)d_ws;
    float* agg   = (float*)ws;                          // 25.6 MB
    float* h1    = (float*)(ws + 25600000);             // 25.6 MB
    float* h2    = (float*)(ws + 51200000);             // 25.6 MB
    float* invd  = (float*)(ws + 76800000);             // 200 KB
    int* cnt     = (int*)  (ws + 77000192);             // 200 KB (aliases cursor)
    int* rowptr  = (int*)  (ws + 77200384);             // 200 KB + 4
    int* col     = (int*)  (ws + 77400576);             // 2.4 MB
    // total ~79.8 MB

    // ---- CSR build (per call; edge_index is an input) ----
    hipMemsetAsync(cnt, 0, NN * sizeof(int), stream);
    count_kernel<<<(E + 255) / 256, 256, 0, stream>>>(dst, cnt, E);
    scan_kernel<<<1, 1024, 0, stream>>>(cnt, rowptr, invd, NN);
    fill_kernel<<<(E + 255) / 256, 256, 0, stream>>>(src, dst, cnt, col, E);

    const int gatherBlocks = (NN * 32 + 255) / 256;
    const int gemmBlocks = (NN + 31) / 32;

    // layer 1: x -> h1, relu
    gather_kernel<<<gatherBlocks, 256, 0, stream>>>(rowptr, col, x, agg, NN);
    sage_gemm<128, 128, true>
        <<<gemmBlocks, 128, 0, stream>>>(agg, x, invd, w1n, w1r, b1, h1, NN);

    // layer 2: h1 -> h2, relu
    gather_kernel<<<gatherBlocks, 256, 0, stream>>>(rowptr, col, h1, agg, NN);
    sage_gemm<128, 128, true>
        <<<gemmBlocks, 128, 0, stream>>>(agg, h1, invd, w2n, w2r, b2, h2, NN);

    // layer 3: h2 -> out (fp32), no relu
    gather_kernel<<<gatherBlocks, 256, 0, stream>>>(rowptr, col, h2, agg, NN);
    sage_gemm<128, 64, false>
        <<<gemmBlocks, 64, 0, stream>>>(agg, h2, invd, w3n, w3r, b3, out, NN);
}

// Round 4
// 475.053 us; speedup vs baseline: 8.1536x; 2.3105x over previous
//
#include <hip/hip_runtime.h>
#include <hip/hip_bf16.h>

#define NN 50000

typedef short bf16x8 __attribute__((ext_vector_type(8)));
typedef float f32x4 __attribute__((ext_vector_type(4)));

// ---------- helpers ----------
__device__ __forceinline__ float bf_lo(unsigned int p) {
    union { unsigned int u; float f; } c; c.u = p << 16; return c.f;
}
__device__ __forceinline__ float bf_hi(unsigned int p) {
    union { unsigned int u; float f; } c; c.u = p & 0xffff0000u; return c.f;
}
__device__ __forceinline__ unsigned short bfbits(float f) {
    __hip_bfloat16 h = __float2bfloat16(f);   // RNE
    union { __hip_bfloat16 b; unsigned short s; } c; c.b = h; return c.s;
}
__device__ __forceinline__ unsigned int pack_bf(float a, float b) {
    return (unsigned int)bfbits(a) | ((unsigned int)bfbits(b) << 16);
}
__device__ __forceinline__ void stv(float* p, float v) { *p = v; }
__device__ __forceinline__ void stv(unsigned short* p, float v) { *p = bfbits(v); }

// ---------- CSR build ----------
__global__ void count_kernel(const int* __restrict__ dst, int* __restrict__ cnt, int E) {
    int e = blockIdx.x * blockDim.x + threadIdx.x;
    if (e < E) atomicAdd(&cnt[dst[e]], 1);
}

__global__ __launch_bounds__(1024) void scan_kernel(
    int* __restrict__ cnt_cursor, int* __restrict__ rowptr,
    float* __restrict__ invd, int n) {
    __shared__ int part[1024];
    const int t = threadIdx.x;
    const int chunk = (n + 1023) / 1024;
    const int beg = t * chunk;
    const int end = min(beg + chunk, n);
    int s = 0;
    for (int i = beg; i < end; i++) s += cnt_cursor[i];
    part[t] = s;
    __syncthreads();
    for (int off = 1; off < 1024; off <<= 1) {
        int v = (t >= off) ? part[t - off] : 0;
        __syncthreads();
        part[t] += v;
        __syncthreads();
    }
    int run = (t == 0) ? 0 : part[t - 1];
    for (int i = beg; i < end; i++) {
        int c = cnt_cursor[i];
        rowptr[i] = run;
        cnt_cursor[i] = run;                 // cursor init (aliases cnt)
        invd[i] = 1.0f / fmaxf((float)c, 1.0f);
        run += c;
    }
    if (t == 1023) rowptr[n] = run;          // == E
}

__global__ void fill_kernel(const int* __restrict__ src, const int* __restrict__ dst,
                            int* __restrict__ cursor, int* __restrict__ col, int E) {
    int e = blockIdx.x * blockDim.x + threadIdx.x;
    if (e < E) {
        int p = atomicAdd(&cursor[dst[e]], 1);
        col[p] = src[e];
    }
}

// ---------- fp32 -> bf16 feature convert ----------
__global__ void cvt_kernel(const float* __restrict__ x, unsigned short* __restrict__ xb,
                           int n4) {
    int i = blockIdx.x * blockDim.x + threadIdx.x;
    if (i >= n4) return;
    float4 v = *(const float4*)(x + 4 * (size_t)i);
    uint2 p = {pack_bf(v.x, v.y), pack_bf(v.z, v.w)};
    *(uint2*)(xb + 4 * (size_t)i) = p;
}

// ---------- combined weight pack: wB[row][0..127]=wn[row], [128..255]=wr[row] ----------
__global__ void wb_kernel(const float* __restrict__ wn, const float* __restrict__ wr,
                          unsigned short* __restrict__ wB, int n4) {  // n4 = N*128/4
    int i = blockIdx.x * blockDim.x + threadIdx.x;
    if (i >= n4) return;
    int row = i >> 5;            // 32 float4-chunks per 128-wide row
    int j = (i & 31) * 4;
    float4 a = *(const float4*)(wn + (size_t)row * 128 + j);
    float4 b = *(const float4*)(wr + (size_t)row * 128 + j);
    uint2 pa = {pack_bf(a.x, a.y), pack_bf(a.z, a.w)};
    uint2 pb = {pack_bf(b.x, b.y), pack_bf(b.z, b.w)};
    *(uint2*)(wB + (size_t)row * 256 + j) = pa;
    *(uint2*)(wB + (size_t)row * 256 + 128 + j) = pb;
}

// ---------- CSR gather (bf16 in, fp32 accum) -> axc[n] = [agg*invd | h[n]] bf16 ----------
__global__ __launch_bounds__(256) void gather_kernel(
    const int* __restrict__ rowptr, const int* __restrict__ col,
    const unsigned short* __restrict__ h,      // [M][128] bf16
    const float* __restrict__ invd,
    unsigned short* __restrict__ axc,          // [M][256] bf16
    int n_nodes) {
    int tid = blockIdx.x * blockDim.x + threadIdx.x;
    int n = tid >> 5;
    if (n >= n_nodes) return;
    int c = (tid & 31) << 2;                   // 4 bf16 per lane
    int beg = rowptr[n], end = rowptr[n + 1];
    float a0 = 0.f, a1 = 0.f, a2 = 0.f, a3 = 0.f;
    int i = beg;
    for (; i + 1 < end; i += 2) {
        int s0 = col[i], s1 = col[i + 1];
        uint2 u0 = *(const uint2*)(h + (size_t)s0 * 128 + c);
        uint2 u1 = *(const uint2*)(h + (size_t)s1 * 128 + c);
        a0 += bf_lo(u0.x) + bf_lo(u1.x); a1 += bf_hi(u0.x) + bf_hi(u1.x);
        a2 += bf_lo(u0.y) + bf_lo(u1.y); a3 += bf_hi(u0.y) + bf_hi(u1.y);
    }
    if (i < end) {
        int s = col[i];
        uint2 u = *(const uint2*)(h + (size_t)s * 128 + c);
        a0 += bf_lo(u.x); a1 += bf_hi(u.x);
        a2 += bf_lo(u.y); a3 += bf_hi(u.y);
    }
    float s = invd[n];
    uint2 p = {pack_bf(a0 * s, a1 * s), pack_bf(a2 * s, a3 * s)};
    *(uint2*)(axc + (size_t)n * 256 + c) = p;
    // root copy
    uint2 r = *(const uint2*)(h + (size_t)n * 128 + c);
    *(uint2*)(axc + (size_t)n * 256 + 128 + c) = r;
}

// ---------- MFMA GEMM: out[M][N] = A[M][256] @ B[N][256]^T + bias (+relu) ----------
// 128x64 tile, 4 waves, 16x16x32 bf16 MFMA, B-slab LDS-resident, A staged BK=64.
template <bool RELU, typename OUT_T>
__global__ __launch_bounds__(256) void mfma_gemm(
    const unsigned short* __restrict__ A,   // [M][256] bf16
    const unsigned short* __restrict__ B,   // [N][256] bf16
    const float* __restrict__ bias,         // [N]
    OUT_T* __restrict__ out,                // [M][N]
    int M, int N, int nTilesN) {
    __shared__ unsigned short As[128 * 72];     // 64 + 8 pad (16B-aligned rows, 2-way free)
    __shared__ unsigned short Bs[64 * 264];     // 256 + 8 pad
    const int t = threadIdx.x;
    const int w = t >> 6, l = t & 63;
    const int tileM = blockIdx.x / nTilesN;
    const int n0 = (blockIdx.x - tileM * nTilesN) * 64;
    const int m0 = tileM * 128;
    const int lr = l & 15, lq = l >> 4;

    // stage B slab [64][256]
    for (int c = t; c < 2048; c += 256) {
        int row = c >> 5;
        int ko = (c & 31) * 8;
        *(uint4*)(&Bs[row * 264 + ko]) =
            *(const uint4*)(&B[(size_t)(n0 + row) * 256 + ko]);
    }

    f32x4 zero = {0.f, 0.f, 0.f, 0.f};
    f32x4 acc[2][4];
#pragma unroll
    for (int tm = 0; tm < 2; tm++)
#pragma unroll
        for (int tn = 0; tn < 4; tn++) acc[tm][tn] = zero;

    for (int ks = 0; ks < 4; ks++) {
        __syncthreads();     // protect As reads of previous iter (and Bs publish at ks=0)
        // stage A slab [128][64]
        for (int c = t; c < 1024; c += 256) {
            int row = c >> 3;
            int ko = (c & 7) * 8;
            int gm = m0 + row;
            uint4 v = {0u, 0u, 0u, 0u};
            if (gm < M) v = *(const uint4*)(&A[(size_t)gm * 256 + ks * 64 + ko]);
            *(uint4*)(&As[row * 72 + ko]) = v;
        }
        __syncthreads();
#pragma unroll
        for (int kc = 0; kc < 2; kc++) {
            int lk = kc * 32 + lq * 8;
            bf16x8 af[2], bfr[4];
            af[0] = *(const bf16x8*)(&As[(w * 32 + lr) * 72 + lk]);
            af[1] = *(const bf16x8*)(&As[(w * 32 + 16 + lr) * 72 + lk]);
#pragma unroll
            for (int tn = 0; tn < 4; tn++)
                bfr[tn] = *(const bf16x8*)(&Bs[(tn * 16 + lr) * 264 + ks * 64 + lk]);
#pragma unroll
            for (int tm = 0; tm < 2; tm++)
#pragma unroll
                for (int tn = 0; tn < 4; tn++)
                    acc[tm][tn] = __builtin_amdgcn_mfma_f32_16x16x32_bf16(
                        af[tm], bfr[tn], acc[tm][tn], 0, 0, 0);
        }
    }

    // epilogue: C/D layout col = lane&15, row = (lane>>4)*4 + reg  [m89/m91]
#pragma unroll
    for (int tn = 0; tn < 4; tn++) {
        int n = n0 + tn * 16 + lr;
        float bj = bias[n];
#pragma unroll
        for (int tm = 0; tm < 2; tm++) {
#pragma unroll
            for (int i = 0; i < 4; i++) {
                int m = m0 + w * 32 + tm * 16 + lq * 4 + i;
                if (m < M) {
                    float v = acc[tm][tn][i] + bj;
                    if (RELU) v = fmaxf(v, 0.f);
                    stv(&out[(size_t)m * N + n], v);
                }
            }
        }
    }
}

extern "C" void kernel_launch(void* const* d_in, const int* in_sizes, int n_in,
                              void* d_out, int out_size, void* d_ws, size_t ws_size,
                              hipStream_t stream) {
    const float* x  = (const float*)d_in[0];
    const int* ei   = (const int*)d_in[1];
    const float* w1n = (const float*)d_in[2];
    const float* w1r = (const float*)d_in[3];
    const float* b1  = (const float*)d_in[4];
    const float* w2n = (const float*)d_in[5];
    const float* w2r = (const float*)d_in[6];
    const float* b2  = (const float*)d_in[7];
    const float* w3n = (const float*)d_in[8];
    const float* w3r = (const float*)d_in[9];
    const float* b3  = (const float*)d_in[10];
    float* out = (float*)d_out;

    const int E = in_sizes[1] / 2;
    const int* src = ei;
    const int* dst = ei + E;

    // workspace layout (all 16B-aligned)
    char* ws = (char*)d_ws;
    unsigned short* xb  = (unsigned short*)(ws);               // 12.8 MB  [M][128]
    unsigned short* axc = (unsigned short*)(ws + 12800000);    // 25.6 MB  [M][256]
    unsigned short* h1b = (unsigned short*)(ws + 38400000);    // 12.8 MB
    unsigned short* h2b = (unsigned short*)(ws + 51200000);    // 12.8 MB
    float* invd         = (float*)(ws + 64000000);             // 200 KB
    int* cnt            = (int*)  (ws + 64200064);             // 200 KB (aliases cursor)
    int* rowptr         = (int*)  (ws + 64400128);             // 200 KB + 4
    int* col            = (int*)  (ws + 64600256);             // 2.4 MB
    unsigned short* wB1 = (unsigned short*)(ws + 67000320);    // 64 KB [128][256]
    unsigned short* wB2 = (unsigned short*)(ws + 67065856);    // 64 KB
    unsigned short* wB3 = (unsigned short*)(ws + 67131392);    // 32 KB [64][256]

    // ---- CSR build ----
    hipMemsetAsync(cnt, 0, NN * sizeof(int), stream);
    count_kernel<<<(E + 255) / 256, 256, 0, stream>>>(dst, cnt, E);
    scan_kernel<<<1, 1024, 0, stream>>>(cnt, rowptr, invd, NN);
    fill_kernel<<<(E + 255) / 256, 256, 0, stream>>>(src, dst, cnt, col, E);

    // ---- precompute bf16 operands ----
    cvt_kernel<<<(NN * 32 + 255) / 256, 256, 0, stream>>>(x, xb, NN * 32);
    wb_kernel<<<(128 * 32 + 255) / 256, 256, 0, stream>>>(w1n, w1r, wB1, 128 * 32);
    wb_kernel<<<(128 * 32 + 255) / 256, 256, 0, stream>>>(w2n, w2r, wB2, 128 * 32);
    wb_kernel<<<(64 * 32 + 255) / 256, 256, 0, stream>>>(w3n, w3r, wB3, 64 * 32);

    const int gatherBlocks = NN * 32 / 256;        // 6250
    const int mTiles = (NN + 127) / 128;           // 391

    // layer 1
    gather_kernel<<<gatherBlocks, 256, 0, stream>>>(rowptr, col, xb, invd, axc, NN);
    mfma_gemm<true, unsigned short>
        <<<mTiles * 2, 256, 0, stream>>>(axc, wB1, b1, h1b, NN, 128, 2);

    // layer 2
    gather_kernel<<<gatherBlocks, 256, 0, stream>>>(rowptr, col, h1b, invd, axc, NN);
    mfma_gemm<true, unsigned short>
        <<<mTiles * 2, 256, 0, stream>>>(axc, wB2, b2, h2b, NN, 128, 2);

    // layer 3 (fp32 out, no relu)
    gather_kernel<<<gatherBlocks, 256, 0, stream>>>(rowptr, col, h2b, invd, axc, NN);
    mfma_gemm<false, float>
        <<<mTiles, 256, 0, stream>>>(axc, wB3, b3, out, NN, 64, 1);
}

// Round 5
// 315.757 us; speedup vs baseline: 12.2670x; 1.5045x over previous
//
#include <hip/hip_runtime.h>
#include <hip/hip_bf16.h>

#define NN 50000

typedef short bf16x8 __attribute__((ext_vector_type(8)));
typedef float f32x4 __attribute__((ext_vector_type(4)));

// ---------- helpers ----------
__device__ __forceinline__ float bf_lo(unsigned int p) {
    union { unsigned int u; float f; } c; c.u = p << 16; return c.f;
}
__device__ __forceinline__ float bf_hi(unsigned int p) {
    union { unsigned int u; float f; } c; c.u = p & 0xffff0000u; return c.f;
}
__device__ __forceinline__ unsigned short bfbits(float f) {
    __hip_bfloat16 h = __float2bfloat16(f);   // RNE
    union { __hip_bfloat16 b; unsigned short s; } c; c.b = h; return c.s;
}
__device__ __forceinline__ unsigned int pack_bf(float a, float b) {
    return (unsigned int)bfbits(a) | ((unsigned int)bfbits(b) << 16);
}
__device__ __forceinline__ void stv(float* p, float v) { *p = v; }
__device__ __forceinline__ void stv(unsigned short* p, float v) { *p = bfbits(v); }

// ---------- CSR build ----------
__global__ void count_kernel(const int* __restrict__ dst, int* __restrict__ cnt, int E) {
    int e = blockIdx.x * blockDim.x + threadIdx.x;
    if (e < E) atomicAdd(&cnt[dst[e]], 1);
}

// hierarchical scan: (1) per-block scan, (2) block-sum scan, (3) apply offsets
__global__ __launch_bounds__(256) void scan1_kernel(
    const int* __restrict__ cnt, int* __restrict__ rowptr,
    int* __restrict__ bsum, int n) {
    __shared__ int sh[256];
    const int t = threadIdx.x;
    const int i = blockIdx.x * 256 + t;
    int v = (i < n) ? cnt[i] : 0;
    sh[t] = v;
    __syncthreads();
    for (int off = 1; off < 256; off <<= 1) {
        int u = (t >= off) ? sh[t - off] : 0;
        __syncthreads();
        sh[t] += u;
        __syncthreads();
    }
    if (i < n) rowptr[i] = sh[t] - v;            // intra-block exclusive
    if (t == 255) bsum[blockIdx.x] = sh[255];
}

__global__ __launch_bounds__(256) void scan2_kernel(
    const int* __restrict__ bsum, int* __restrict__ boff,
    int* __restrict__ rowptr, int nb, int n) {
    __shared__ int sh[256];
    const int t = threadIdx.x;
    int v = (t < nb) ? bsum[t] : 0;
    sh[t] = v;
    __syncthreads();
    for (int off = 1; off < 256; off <<= 1) {
        int u = (t >= off) ? sh[t - off] : 0;
        __syncthreads();
        sh[t] += u;
        __syncthreads();
    }
    if (t < nb) boff[t] = sh[t] - v;             // exclusive block offset
    if (t == 255) rowptr[n] = sh[255];           // total == E
}

__global__ __launch_bounds__(256) void scan3_kernel(
    const int* __restrict__ cnt, int* __restrict__ rowptr,
    int* __restrict__ cursor, float* __restrict__ invd,
    const int* __restrict__ boff, int n) {
    const int i = blockIdx.x * 256 + threadIdx.x;
    if (i >= n) return;
    int f = rowptr[i] + boff[blockIdx.x];
    rowptr[i] = f;
    cursor[i] = f;
    invd[i] = 1.0f / fmaxf((float)cnt[i], 1.0f);
}

__global__ void fill_kernel(const int* __restrict__ src, const int* __restrict__ dst,
                            int* __restrict__ cursor, int* __restrict__ col, int E) {
    int e = blockIdx.x * blockDim.x + threadIdx.x;
    if (e < E) {
        int p = atomicAdd(&cursor[dst[e]], 1);
        col[p] = src[e];
    }
}

// ---------- fp32 -> bf16 feature convert ----------
__global__ void cvt_kernel(const float* __restrict__ x, unsigned short* __restrict__ xb,
                           int n4) {
    int i = blockIdx.x * blockDim.x + threadIdx.x;
    if (i >= n4) return;
    float4 v = *(const float4*)(x + 4 * (size_t)i);
    uint2 p = {pack_bf(v.x, v.y), pack_bf(v.z, v.w)};
    *(uint2*)(xb + 4 * (size_t)i) = p;
}

// ---------- combined weight pack: wB[row][0..127]=wn[row], [128..255]=wr[row] ----------
__global__ void wb_kernel(const float* __restrict__ wn, const float* __restrict__ wr,
                          unsigned short* __restrict__ wB, int n4) {  // n4 = N*128/4
    int i = blockIdx.x * blockDim.x + threadIdx.x;
    if (i >= n4) return;
    int row = i >> 5;
    int j = (i & 31) * 4;
    float4 a = *(const float4*)(wn + (size_t)row * 128 + j);
    float4 b = *(const float4*)(wr + (size_t)row * 128 + j);
    uint2 pa = {pack_bf(a.x, a.y), pack_bf(a.z, a.w)};
    uint2 pb = {pack_bf(b.x, b.y), pack_bf(b.z, b.w)};
    *(uint2*)(wB + (size_t)row * 256 + j) = pa;
    *(uint2*)(wB + (size_t)row * 256 + 128 + j) = pb;
}

// ---------- CSR gather: 16 lanes x uint4(16B) per node ----------
__global__ __launch_bounds__(256) void gather_kernel(
    const int* __restrict__ rowptr, const int* __restrict__ col,
    const unsigned short* __restrict__ h,      // [M][128] bf16
    const float* __restrict__ invd,
    unsigned short* __restrict__ axc,          // [M][256] bf16
    int n_nodes) {
    int tid = blockIdx.x * blockDim.x + threadIdx.x;
    int n = tid >> 4;
    if (n >= n_nodes) return;
    int c = (tid & 15) << 3;                   // 8 bf16 per lane
    int beg = rowptr[n], end = rowptr[n + 1];
    float a0 = 0.f, a1 = 0.f, a2 = 0.f, a3 = 0.f;
    float a4 = 0.f, a5 = 0.f, a6 = 0.f, a7 = 0.f;
    int i = beg;
    for (; i + 1 < end; i += 2) {
        int s0 = col[i], s1 = col[i + 1];
        uint4 u = *(const uint4*)(h + (size_t)s0 * 128 + c);
        uint4 v = *(const uint4*)(h + (size_t)s1 * 128 + c);
        a0 += bf_lo(u.x) + bf_lo(v.x); a1 += bf_hi(u.x) + bf_hi(v.x);
        a2 += bf_lo(u.y) + bf_lo(v.y); a3 += bf_hi(u.y) + bf_hi(v.y);
        a4 += bf_lo(u.z) + bf_lo(v.z); a5 += bf_hi(u.z) + bf_hi(v.z);
        a6 += bf_lo(u.w) + bf_lo(v.w); a7 += bf_hi(u.w) + bf_hi(v.w);
    }
    if (i < end) {
        uint4 u = *(const uint4*)(h + (size_t)col[i] * 128 + c);
        a0 += bf_lo(u.x); a1 += bf_hi(u.x);
        a2 += bf_lo(u.y); a3 += bf_hi(u.y);
        a4 += bf_lo(u.z); a5 += bf_hi(u.z);
        a6 += bf_lo(u.w); a7 += bf_hi(u.w);
    }
    float s = invd[n];
    uint4 p = {pack_bf(a0 * s, a1 * s), pack_bf(a2 * s, a3 * s),
               pack_bf(a4 * s, a5 * s), pack_bf(a6 * s, a7 * s)};
    *(uint4*)(axc + (size_t)n * 256 + c) = p;
    // root copy
    uint4 r = *(const uint4*)(h + (size_t)n * 128 + c);
    *(uint4*)(axc + (size_t)n * 256 + 128 + c) = r;
}

// ---------- MFMA GEMM: out[M][N] = A[M][256] @ B[N][256]^T + bias (+relu) ----------
template <bool RELU, typename OUT_T>
__global__ __launch_bounds__(256) void mfma_gemm(
    const unsigned short* __restrict__ A,   // [M][256] bf16
    const unsigned short* __restrict__ B,   // [N][256] bf16
    const float* __restrict__ bias,         // [N]
    OUT_T* __restrict__ out,                // [M][N]
    int M, int N, int nTilesN) {
    __shared__ unsigned short As[128 * 72];
    __shared__ unsigned short Bs[64 * 264];
    const int t = threadIdx.x;
    const int w = t >> 6, l = t & 63;
    const int tileM = blockIdx.x / nTilesN;
    const int n0 = (blockIdx.x - tileM * nTilesN) * 64;
    const int m0 = tileM * 128;
    const int lr = l & 15, lq = l >> 4;

    for (int c = t; c < 2048; c += 256) {
        int row = c >> 5;
        int ko = (c & 31) * 8;
        *(uint4*)(&Bs[row * 264 + ko]) =
            *(const uint4*)(&B[(size_t)(n0 + row) * 256 + ko]);
    }

    f32x4 zero = {0.f, 0.f, 0.f, 0.f};
    f32x4 acc[2][4];
#pragma unroll
    for (int tm = 0; tm < 2; tm++)
#pragma unroll
        for (int tn = 0; tn < 4; tn++) acc[tm][tn] = zero;

    for (int ks = 0; ks < 4; ks++) {
        __syncthreads();
        for (int c = t; c < 1024; c += 256) {
            int row = c >> 3;
            int ko = (c & 7) * 8;
            int gm = m0 + row;
            uint4 v = {0u, 0u, 0u, 0u};
            if (gm < M) v = *(const uint4*)(&A[(size_t)gm * 256 + ks * 64 + ko]);
            *(uint4*)(&As[row * 72 + ko]) = v;
        }
        __syncthreads();
#pragma unroll
        for (int kc = 0; kc < 2; kc++) {
            int lk = kc * 32 + lq * 8;
            bf16x8 af[2], bfr[4];
            af[0] = *(const bf16x8*)(&As[(w * 32 + lr) * 72 + lk]);
            af[1] = *(const bf16x8*)(&As[(w * 32 + 16 + lr) * 72 + lk]);
#pragma unroll
            for (int tn = 0; tn < 4; tn++)
                bfr[tn] = *(const bf16x8*)(&Bs[(tn * 16 + lr) * 264 + ks * 64 + lk]);
#pragma unroll
            for (int tm = 0; tm < 2; tm++)
#pragma unroll
                for (int tn = 0; tn < 4; tn++)
                    acc[tm][tn] = __builtin_amdgcn_mfma_f32_16x16x32_bf16(
                        af[tm], bfr[tn], acc[tm][tn], 0, 0, 0);
        }
    }

    // epilogue: C/D layout col = lane&15, row = (lane>>4)*4 + reg  [m89/m91]
#pragma unroll
    for (int tn = 0; tn < 4; tn++) {
        int n = n0 + tn * 16 + lr;
        float bj = bias[n];
#pragma unroll
        for (int tm = 0; tm < 2; tm++) {
#pragma unroll
            for (int i = 0; i < 4; i++) {
                int m = m0 + w * 32 + tm * 16 + lq * 4 + i;
                if (m < M) {
                    float v = acc[tm][tn][i] + bj;
                    if (RELU) v = fmaxf(v, 0.f);
                    stv(&out[(size_t)m * N + n], v);
                }
            }
        }
    }
}

extern "C" void kernel_launch(void* const* d_in, const int* in_sizes, int n_in,
                              void* d_out, int out_size, void* d_ws, size_t ws_size,
                              hipStream_t stream) {
    const float* x  = (const float*)d_in[0];
    const int* ei   = (const int*)d_in[1];
    const float* w1n = (const float*)d_in[2];
    const float* w1r = (const float*)d_in[3];
    const float* b1  = (const float*)d_in[4];
    const float* w2n = (const float*)d_in[5];
    const float* w2r = (const float*)d_in[6];
    const float* b2  = (const float*)d_in[7];
    const float* w3n = (const float*)d_in[8];
    const float* w3r = (const float*)d_in[9];
    const float* b3  = (const float*)d_in[10];
    float* out = (float*)d_out;

    const int E = in_sizes[1] / 2;
    const int* src = ei;
    const int* dst = ei + E;

    // workspace layout (all 16B-aligned)
    char* ws = (char*)d_ws;
    unsigned short* xb  = (unsigned short*)(ws);               // 12.8 MB  [M][128]
    unsigned short* axc = (unsigned short*)(ws + 12800000);    // 25.6 MB  [M][256]
    unsigned short* h1b = (unsigned short*)(ws + 38400000);    // 12.8 MB
    unsigned short* h2b = (unsigned short*)(ws + 51200000);    // 12.8 MB
    float* invd         = (float*)(ws + 64000000);             // 200 KB
    int* cnt            = (int*)  (ws + 64200064);             // 200 KB
    int* rowptr         = (int*)  (ws + 64400128);             // 200 KB + 4
    int* cursor         = (int*)  (ws + 64600192);             // 200 KB
    int* col            = (int*)  (ws + 64800256);             // 2.4 MB
    unsigned short* wB1 = (unsigned short*)(ws + 67200256);    // 64 KB [128][256]
    unsigned short* wB2 = (unsigned short*)(ws + 67265792);    // 64 KB
    unsigned short* wB3 = (unsigned short*)(ws + 67331328);    // 32 KB [64][256]
    int* bsum           = (int*)  (ws + 67364096);             // 784 B
    int* boff           = (int*)  (ws + 67364896);             // 784 B

    const int nScanBlocks = (NN + 255) / 256;   // 196

    // ---- CSR build ----
    hipMemsetAsync(cnt, 0, NN * sizeof(int), stream);
    count_kernel<<<(E + 255) / 256, 256, 0, stream>>>(dst, cnt, E);
    scan1_kernel<<<nScanBlocks, 256, 0, stream>>>(cnt, rowptr, bsum, NN);
    scan2_kernel<<<1, 256, 0, stream>>>(bsum, boff, rowptr, nScanBlocks, NN);
    scan3_kernel<<<nScanBlocks, 256, 0, stream>>>(cnt, rowptr, cursor, invd, boff, NN);
    fill_kernel<<<(E + 255) / 256, 256, 0, stream>>>(src, dst, cursor, col, E);

    // ---- precompute bf16 operands ----
    cvt_kernel<<<(NN * 32 + 255) / 256, 256, 0, stream>>>(x, xb, NN * 32);
    wb_kernel<<<(128 * 32 + 255) / 256, 256, 0, stream>>>(w1n, w1r, wB1, 128 * 32);
    wb_kernel<<<(128 * 32 + 255) / 256, 256, 0, stream>>>(w2n, w2r, wB2, 128 * 32);
    wb_kernel<<<(64 * 32 + 255) / 256, 256, 0, stream>>>(w3n, w3r, wB3, 64 * 32);

    const int gatherBlocks = NN * 16 / 256;        // 3125
    const int mTiles = (NN + 127) / 128;           // 391

    // layer 1
    gather_kernel<<<gatherBlocks, 256, 0, stream>>>(rowptr, col, xb, invd, axc, NN);
    mfma_gemm<true, unsigned short>
        <<<mTiles * 2, 256, 0, stream>>>(axc, wB1, b1, h1b, NN, 128, 2);

    // layer 2
    gather_kernel<<<gatherBlocks, 256, 0, stream>>>(rowptr, col, h1b, invd, axc, NN);
    mfma_gemm<true, unsigned short>
        <<<mTiles * 2, 256, 0, stream>>>(axc, wB2, b2, h2b, NN, 128, 2);

    // layer 3 (fp32 out, no relu)
    gather_kernel<<<gatherBlocks, 256, 0, stream>>>(rowptr, col, h2b, invd, axc, NN);
    mfma_gemm<false, float>
        <<<mTiles, 256, 0, stream>>>(axc, wB3, b3, out, NN, 64, 1);
}

// Round 6
// 297.558 us; speedup vs baseline: 13.0173x; 1.0612x over previous
//
#include <hip/hip_runtime.h>
#include <hip/hip_bf16.h>

#define NN 50000

typedef short bf16x8 __attribute__((ext_vector_type(8)));
typedef float f32x4 __attribute__((ext_vector_type(4)));

// ---------- helpers ----------
__device__ __forceinline__ float bf_lo(unsigned int p) {
    union { unsigned int u; float f; } c; c.u = p << 16; return c.f;
}
__device__ __forceinline__ float bf_hi(unsigned int p) {
    union { unsigned int u; float f; } c; c.u = p & 0xffff0000u; return c.f;
}
__device__ __forceinline__ unsigned short bfbits(float f) {
    __hip_bfloat16 h = __float2bfloat16(f);   // RNE
    union { __hip_bfloat16 b; unsigned short s; } c; c.b = h; return c.s;
}
__device__ __forceinline__ unsigned int pack_bf(float a, float b) {
    return (unsigned int)bfbits(a) | ((unsigned int)bfbits(b) << 16);
}
__device__ __forceinline__ void stv(float* p, float v) { *p = v; }
__device__ __forceinline__ void stv(unsigned short* p, float v) { *p = bfbits(v); }

// ---------- CSR build ----------
__global__ void count_kernel(const int* __restrict__ dst, int* __restrict__ cnt, int E) {
    int e = blockIdx.x * blockDim.x + threadIdx.x;
    if (e < E) atomicAdd(&cnt[dst[e]], 1);
}

// (1) per-block inclusive scan -> intra-block exclusive prefixes + block sums
__global__ __launch_bounds__(256) void scan1_kernel(
    const int* __restrict__ cnt, int* __restrict__ rowptr,
    int* __restrict__ bsum, int n) {
    __shared__ int sh[256];
    const int t = threadIdx.x;
    const int i = blockIdx.x * 256 + t;
    int v = (i < n) ? cnt[i] : 0;
    sh[t] = v;
    __syncthreads();
    for (int off = 1; off < 256; off <<= 1) {
        int u = (t >= off) ? sh[t - off] : 0;
        __syncthreads();
        sh[t] += u;
        __syncthreads();
    }
    if (i < n) rowptr[i] = sh[t] - v;            // intra-block exclusive
    if (t == 255) bsum[blockIdx.x] = sh[255];
}

// (2+3) each block reduces bsum[0..blockIdx) itself, applies offset, emits
// rowptr/cursor/invd; last block writes rowptr[n] = E.
__global__ __launch_bounds__(256) void scan23_kernel(
    const int* __restrict__ cnt, int* __restrict__ rowptr,
    int* __restrict__ cursor, float* __restrict__ invd,
    const int* __restrict__ bsum, int nb, int n) {
    __shared__ int sh[256];
    const int t = threadIdx.x;
    const int b = blockIdx.x;
    sh[t] = (t < b) ? bsum[t] : 0;               // b <= nb-1 < 256
    __syncthreads();
    for (int off = 128; off >= 1; off >>= 1) {
        if (t < off) sh[t] += sh[t + off];
        __syncthreads();
    }
    const int boff = sh[0];                      // exclusive prefix of block sums
    const int i = b * 256 + t;
    if (i < n) {
        int f = rowptr[i] + boff;
        rowptr[i] = f;
        cursor[i] = f;
        invd[i] = 1.0f / fmaxf((float)cnt[i], 1.0f);
    }
    if (b == nb - 1 && t == 0) rowptr[n] = boff + bsum[b];   // == E
}

__global__ void fill_kernel(const int* __restrict__ src, const int* __restrict__ dst,
                            int* __restrict__ cursor, int* __restrict__ col, int E) {
    int e = blockIdx.x * blockDim.x + threadIdx.x;
    if (e < E) {
        int p = atomicAdd(&cursor[dst[e]], 1);
        col[p] = src[e];
    }
}

// ---------- fp32 -> bf16 feature convert (+ zero cnt, saving a memset) ----------
__global__ void cvt_kernel(const float* __restrict__ x, unsigned short* __restrict__ xb,
                           int* __restrict__ cnt, int n4) {
    int i = blockIdx.x * blockDim.x + threadIdx.x;
    if (i < NN) cnt[i] = 0;
    if (i >= n4) return;
    float4 v = *(const float4*)(x + 4 * (size_t)i);
    uint2 p = {pack_bf(v.x, v.y), pack_bf(v.z, v.w)};
    *(uint2*)(xb + 4 * (size_t)i) = p;
}

// ---------- all-3-layer weight pack: wB[row] = [wn_row | wr_row] bf16 ----------
__global__ __launch_bounds__(256) void wb3_kernel(
    const float* __restrict__ w1n, const float* __restrict__ w1r,
    const float* __restrict__ w2n, const float* __restrict__ w2r,
    const float* __restrict__ w3n, const float* __restrict__ w3r,
    unsigned short* __restrict__ wB1, unsigned short* __restrict__ wB2,
    unsigned short* __restrict__ wB3) {
    int i = blockIdx.x * blockDim.x + threadIdx.x;   // 10240 total chunks
    const float *wn, *wr;
    unsigned short* wB;
    int li;
    if (i < 4096)      { wn = w1n; wr = w1r; wB = wB1; li = i; }
    else if (i < 8192) { wn = w2n; wr = w2r; wB = wB2; li = i - 4096; }
    else if (i < 10240){ wn = w3n; wr = w3r; wB = wB3; li = i - 8192; }
    else return;
    int row = li >> 5;
    int j = (li & 31) * 4;
    float4 a = *(const float4*)(wn + (size_t)row * 128 + j);
    float4 b = *(const float4*)(wr + (size_t)row * 128 + j);
    uint2 pa = {pack_bf(a.x, a.y), pack_bf(a.z, a.w)};
    uint2 pb = {pack_bf(b.x, b.y), pack_bf(b.z, b.w)};
    *(uint2*)(wB + (size_t)row * 256 + j) = pa;
    *(uint2*)(wB + (size_t)row * 256 + 128 + j) = pb;
}

// ---------- CSR gather: 16 lanes x uint4(16B) per node, unroll-4, agg only ----------
__global__ __launch_bounds__(256) void gather_kernel(
    const int* __restrict__ rowptr, const int* __restrict__ col,
    const unsigned short* __restrict__ h,      // [M][128] bf16
    const float* __restrict__ invd,
    unsigned short* __restrict__ axc,          // [M][128] bf16 (agg*invd)
    int n_nodes) {
    int tid = blockIdx.x * blockDim.x + threadIdx.x;
    int n = tid >> 4;
    if (n >= n_nodes) return;
    int c = (tid & 15) << 3;                   // 8 bf16 per lane
    int beg = rowptr[n], end = rowptr[n + 1];
    float a0 = 0.f, a1 = 0.f, a2 = 0.f, a3 = 0.f;
    float a4 = 0.f, a5 = 0.f, a6 = 0.f, a7 = 0.f;
    int i = beg;
    for (; i + 3 < end; i += 4) {
        int s0 = col[i], s1 = col[i + 1], s2 = col[i + 2], s3 = col[i + 3];
        uint4 u0 = *(const uint4*)(h + (size_t)s0 * 128 + c);
        uint4 u1 = *(const uint4*)(h + (size_t)s1 * 128 + c);
        uint4 u2 = *(const uint4*)(h + (size_t)s2 * 128 + c);
        uint4 u3 = *(const uint4*)(h + (size_t)s3 * 128 + c);
        a0 += (bf_lo(u0.x) + bf_lo(u1.x)) + (bf_lo(u2.x) + bf_lo(u3.x));
        a1 += (bf_hi(u0.x) + bf_hi(u1.x)) + (bf_hi(u2.x) + bf_hi(u3.x));
        a2 += (bf_lo(u0.y) + bf_lo(u1.y)) + (bf_lo(u2.y) + bf_lo(u3.y));
        a3 += (bf_hi(u0.y) + bf_hi(u1.y)) + (bf_hi(u2.y) + bf_hi(u3.y));
        a4 += (bf_lo(u0.z) + bf_lo(u1.z)) + (bf_lo(u2.z) + bf_lo(u3.z));
        a5 += (bf_hi(u0.z) + bf_hi(u1.z)) + (bf_hi(u2.z) + bf_hi(u3.z));
        a6 += (bf_lo(u0.w) + bf_lo(u1.w)) + (bf_lo(u2.w) + bf_lo(u3.w));
        a7 += (bf_hi(u0.w) + bf_hi(u1.w)) + (bf_hi(u2.w) + bf_hi(u3.w));
    }
    for (; i < end; i++) {
        uint4 u = *(const uint4*)(h + (size_t)col[i] * 128 + c);
        a0 += bf_lo(u.x); a1 += bf_hi(u.x);
        a2 += bf_lo(u.y); a3 += bf_hi(u.y);
        a4 += bf_lo(u.z); a5 += bf_hi(u.z);
        a6 += bf_lo(u.w); a7 += bf_hi(u.w);
    }
    float s = invd[n];
    uint4 p = {pack_bf(a0 * s, a1 * s), pack_bf(a2 * s, a3 * s),
               pack_bf(a4 * s, a5 * s), pack_bf(a6 * s, a7 * s)};
    *(uint4*)(axc + (size_t)n * 128 + c) = p;
}

// ---------- MFMA GEMM: out = [axc | hroot] @ B[N][256]^T + bias (+relu) ----------
// A's K 0-127 half from axc (agg), K 128-255 half read directly from hroot.
template <bool RELU, typename OUT_T>
__global__ __launch_bounds__(256) void mfma_gemm(
    const unsigned short* __restrict__ axc,    // [M][128] bf16
    const unsigned short* __restrict__ hroot,  // [M][128] bf16
    const unsigned short* __restrict__ B,      // [N][256] bf16
    const float* __restrict__ bias,            // [N]
    OUT_T* __restrict__ out,                   // [M][N]
    int M, int N, int nTilesN) {
    __shared__ unsigned short As[128 * 72];
    __shared__ unsigned short Bs[64 * 264];
    const int t = threadIdx.x;
    const int w = t >> 6, l = t & 63;
    const int tileM = blockIdx.x / nTilesN;
    const int n0 = (blockIdx.x - tileM * nTilesN) * 64;
    const int m0 = tileM * 128;
    const int lr = l & 15, lq = l >> 4;

    for (int c = t; c < 2048; c += 256) {
        int row = c >> 5;
        int ko = (c & 31) * 8;
        *(uint4*)(&Bs[row * 264 + ko]) =
            *(const uint4*)(&B[(size_t)(n0 + row) * 256 + ko]);
    }

    f32x4 zero = {0.f, 0.f, 0.f, 0.f};
    f32x4 acc[2][4];
#pragma unroll
    for (int tm = 0; tm < 2; tm++)
#pragma unroll
        for (int tn = 0; tn < 4; tn++) acc[tm][tn] = zero;

    for (int ks = 0; ks < 4; ks++) {
        const unsigned short* Asrc =
            (ks < 2) ? (axc + (size_t)(ks) * 64) : (hroot + (size_t)(ks - 2) * 64);
        __syncthreads();
        for (int c = t; c < 1024; c += 256) {
            int row = c >> 3;
            int ko = (c & 7) * 8;
            int gm = m0 + row;
            uint4 v = {0u, 0u, 0u, 0u};
            if (gm < M) v = *(const uint4*)(Asrc + (size_t)gm * 128 + ko);
            *(uint4*)(&As[row * 72 + ko]) = v;
        }
        __syncthreads();
#pragma unroll
        for (int kc = 0; kc < 2; kc++) {
            int lk = kc * 32 + lq * 8;
            bf16x8 af[2], bfr[4];
            af[0] = *(const bf16x8*)(&As[(w * 32 + lr) * 72 + lk]);
            af[1] = *(const bf16x8*)(&As[(w * 32 + 16 + lr) * 72 + lk]);
#pragma unroll
            for (int tn = 0; tn < 4; tn++)
                bfr[tn] = *(const bf16x8*)(&Bs[(tn * 16 + lr) * 264 + ks * 64 + lk]);
#pragma unroll
            for (int tm = 0; tm < 2; tm++)
#pragma unroll
                for (int tn = 0; tn < 4; tn++)
                    acc[tm][tn] = __builtin_amdgcn_mfma_f32_16x16x32_bf16(
                        af[tm], bfr[tn], acc[tm][tn], 0, 0, 0);
        }
    }

    // epilogue: C/D layout col = lane&15, row = (lane>>4)*4 + reg  [m89/m91]
#pragma unroll
    for (int tn = 0; tn < 4; tn++) {
        int n = n0 + tn * 16 + lr;
        float bj = bias[n];
#pragma unroll
        for (int tm = 0; tm < 2; tm++) {
#pragma unroll
            for (int i = 0; i < 4; i++) {
                int m = m0 + w * 32 + tm * 16 + lq * 4 + i;
                if (m < M) {
                    float v = acc[tm][tn][i] + bj;
                    if (RELU) v = fmaxf(v, 0.f);
                    stv(&out[(size_t)m * N + n], v);
                }
            }
        }
    }
}

extern "C" void kernel_launch(void* const* d_in, const int* in_sizes, int n_in,
                              void* d_out, int out_size, void* d_ws, size_t ws_size,
                              hipStream_t stream) {
    const float* x  = (const float*)d_in[0];
    const int* ei   = (const int*)d_in[1];
    const float* w1n = (const float*)d_in[2];
    const float* w1r = (const float*)d_in[3];
    const float* b1  = (const float*)d_in[4];
    const float* w2n = (const float*)d_in[5];
    const float* w2r = (const float*)d_in[6];
    const float* b2  = (const float*)d_in[7];
    const float* w3n = (const float*)d_in[8];
    const float* w3r = (const float*)d_in[9];
    const float* b3  = (const float*)d_in[10];
    float* out = (float*)d_out;

    const int E = in_sizes[1] / 2;
    const int* src = ei;
    const int* dst = ei + E;

    // workspace layout (16B-aligned)
    char* ws = (char*)d_ws;
    unsigned short* xb  = (unsigned short*)(ws);               // 12.8 MB [M][128]
    unsigned short* axc = (unsigned short*)(ws + 12800000);    // 12.8 MB [M][128]
    unsigned short* h1b = (unsigned short*)(ws + 25600000);    // 12.8 MB
    unsigned short* h2b = (unsigned short*)(ws + 38400000);    // 12.8 MB
    float* invd         = (float*)(ws + 51200000);             // 200 KB
    int* cnt            = (int*)  (ws + 51404800);             // 200 KB
    int* rowptr         = (int*)  (ws + 51609600);             // 200 KB + 4
    int* cursor         = (int*)  (ws + 51814400);             // 200 KB
    int* col            = (int*)  (ws + 52019200);             // 2.4 MB
    unsigned short* wB1 = (unsigned short*)(ws + 54419200);    // 64 KB [128][256]
    unsigned short* wB2 = (unsigned short*)(ws + 54484736);    // 64 KB
    unsigned short* wB3 = (unsigned short*)(ws + 54550272);    // 32 KB [64][256]
    int* bsum           = (int*)  (ws + 54583040);             // 784 B
    // total ~54.6 MB

    const int nScanBlocks = (NN + 255) / 256;   // 196

    // ---- prep (also zeroes cnt) + CSR build ----
    cvt_kernel<<<(NN * 32 + 255) / 256, 256, 0, stream>>>(x, xb, cnt, NN * 32);
    wb3_kernel<<<40, 256, 0, stream>>>(w1n, w1r, w2n, w2r, w3n, w3r, wB1, wB2, wB3);
    count_kernel<<<(E + 255) / 256, 256, 0, stream>>>(dst, cnt, E);
    scan1_kernel<<<nScanBlocks, 256, 0, stream>>>(cnt, rowptr, bsum, NN);
    scan23_kernel<<<nScanBlocks, 256, 0, stream>>>(cnt, rowptr, cursor, invd, bsum,
                                                   nScanBlocks, NN);
    fill_kernel<<<(E + 255) / 256, 256, 0, stream>>>(src, dst, cursor, col, E);

    const int gatherBlocks = NN * 16 / 256;        // 3125
    const int mTiles = (NN + 127) / 128;           // 391

    // layer 1
    gather_kernel<<<gatherBlocks, 256, 0, stream>>>(rowptr, col, xb, invd, axc, NN);
    mfma_gemm<true, unsigned short>
        <<<mTiles * 2, 256, 0, stream>>>(axc, xb, wB1, b1, h1b, NN, 128, 2);

    // layer 2
    gather_kernel<<<gatherBlocks, 256, 0, stream>>>(rowptr, col, h1b, invd, axc, NN);
    mfma_gemm<true, unsigned short>
        <<<mTiles * 2, 256, 0, stream>>>(axc, h1b, wB2, b2, h2b, NN, 128, 2);

    // layer 3 (fp32 out, no relu)
    gather_kernel<<<gatherBlocks, 256, 0, stream>>>(rowptr, col, h2b, invd, axc, NN);
    mfma_gemm<false, float>
        <<<mTiles, 256, 0, stream>>>(axc, h2b, wB3, b3, out, NN, 64, 1);
}

// Round 7
// 276.325 us; speedup vs baseline: 14.0176x; 1.0768x over previous
//
#include <hip/hip_runtime.h>
#include <hip/hip_bf16.h>

#define NN 50000

typedef short bf16x8 __attribute__((ext_vector_type(8)));
typedef float f32x4 __attribute__((ext_vector_type(4)));

// ---------- helpers ----------
__device__ __forceinline__ float bf_lo(unsigned int p) {
    union { unsigned int u; float f; } c; c.u = p << 16; return c.f;
}
__device__ __forceinline__ float bf_hi(unsigned int p) {
    union { unsigned int u; float f; } c; c.u = p & 0xffff0000u; return c.f;
}
__device__ __forceinline__ unsigned short bfbits(float f) {
    __hip_bfloat16 h = __float2bfloat16(f);   // RNE
    union { __hip_bfloat16 b; unsigned short s; } c; c.b = h; return c.s;
}
__device__ __forceinline__ unsigned int pack_bf(float a, float b) {
    return (unsigned int)bfbits(a) | ((unsigned int)bfbits(b) << 16);
}
__device__ __forceinline__ void stv(float* p, float v) { *p = v; }
__device__ __forceinline__ void stv(unsigned short* p, float v) { *p = bfbits(v); }

// ---------- CSR build ----------
__global__ void count_kernel(const int* __restrict__ dst, int* __restrict__ cnt, int E) {
    int e = blockIdx.x * blockDim.x + threadIdx.x;
    if (e < E) atomicAdd(&cnt[dst[e]], 1);
}

__global__ __launch_bounds__(256) void scan1_kernel(
    const int* __restrict__ cnt, int* __restrict__ rowptr,
    int* __restrict__ bsum, int n) {
    __shared__ int sh[256];
    const int t = threadIdx.x;
    const int i = blockIdx.x * 256 + t;
    int v = (i < n) ? cnt[i] : 0;
    sh[t] = v;
    __syncthreads();
    for (int off = 1; off < 256; off <<= 1) {
        int u = (t >= off) ? sh[t - off] : 0;
        __syncthreads();
        sh[t] += u;
        __syncthreads();
    }
    if (i < n) rowptr[i] = sh[t] - v;            // intra-block exclusive
    if (t == 255) bsum[blockIdx.x] = sh[255];
}

__global__ __launch_bounds__(256) void scan23_kernel(
    const int* __restrict__ cnt, int* __restrict__ rowptr,
    int* __restrict__ cursor, float* __restrict__ invd,
    const int* __restrict__ bsum, int nb, int n) {
    __shared__ int sh[256];
    const int t = threadIdx.x;
    const int b = blockIdx.x;
    sh[t] = (t < b) ? bsum[t] : 0;               // b <= nb-1 < 256
    __syncthreads();
    for (int off = 128; off >= 1; off >>= 1) {
        if (t < off) sh[t] += sh[t + off];
        __syncthreads();
    }
    const int boff = sh[0];
    const int i = b * 256 + t;
    if (i < n) {
        int f = rowptr[i] + boff;
        rowptr[i] = f;
        cursor[i] = f;
        invd[i] = 1.0f / fmaxf((float)cnt[i], 1.0f);
    }
    if (b == nb - 1 && t == 0) rowptr[n] = boff + bsum[b];   // == E
}

__global__ void fill_kernel(const int* __restrict__ src, const int* __restrict__ dst,
                            int* __restrict__ cursor, int* __restrict__ col, int E) {
    int e = blockIdx.x * blockDim.x + threadIdx.x;
    if (e < E) {
        int p = atomicAdd(&cursor[dst[e]], 1);
        col[p] = src[e];
    }
}

// ---------- fp32 -> bf16 feature convert (+ zero cnt) ----------
__global__ void cvt_kernel(const float* __restrict__ x, unsigned short* __restrict__ xb,
                           int* __restrict__ cnt, int n4) {
    int i = blockIdx.x * blockDim.x + threadIdx.x;
    if (i < NN) cnt[i] = 0;
    if (i >= n4) return;
    float4 v = *(const float4*)(x + 4 * (size_t)i);
    uint2 p = {pack_bf(v.x, v.y), pack_bf(v.z, v.w)};
    *(uint2*)(xb + 4 * (size_t)i) = p;
}

// ---------- weight pack ----------
// wB1/wB2: [128][256] = [wn_row | wr_row]; wB3: [128][128] stacked rows [w3n; w3r]
__global__ __launch_bounds__(256) void wb3_kernel(
    const float* __restrict__ w1n, const float* __restrict__ w1r,
    const float* __restrict__ w2n, const float* __restrict__ w2r,
    const float* __restrict__ w3n, const float* __restrict__ w3r,
    unsigned short* __restrict__ wB1, unsigned short* __restrict__ wB2,
    unsigned short* __restrict__ wB3) {
    int i = blockIdx.x * blockDim.x + threadIdx.x;   // 12288 chunks of 4 floats
    if (i >= 12288) return;
    if (i < 8192) {
        const float* wn = (i < 4096) ? w1n : w2n;
        const float* wr = (i < 4096) ? w1r : w2r;
        unsigned short* wB = (i < 4096) ? wB1 : wB2;
        int li = i & 4095;
        int row = li >> 5;
        int j = (li & 31) * 4;
        float4 a = *(const float4*)(wn + (size_t)row * 128 + j);
        float4 b = *(const float4*)(wr + (size_t)row * 128 + j);
        *(uint2*)(wB + (size_t)row * 256 + j) = uint2{pack_bf(a.x, a.y), pack_bf(a.z, a.w)};
        *(uint2*)(wB + (size_t)row * 256 + 128 + j) = uint2{pack_bf(b.x, b.y), pack_bf(b.z, b.w)};
    } else {
        int li = i - 8192;                  // 0..4095: 2048 for w3n, 2048 for w3r
        const float* w = (li < 2048) ? w3n : w3r;
        int rbase = (li < 2048) ? 0 : 64;
        int lj = li & 2047;
        int row = lj >> 5;
        int j = (lj & 31) * 4;
        float4 a = *(const float4*)(w + (size_t)row * 128 + j);
        *(uint2*)(wB3 + (size_t)(rbase + row) * 128 + j) =
            uint2{pack_bf(a.x, a.y), pack_bf(a.z, a.w)};
    }
}

// ---------- CSR gather: 16 lanes x uint4(16B) per node, unroll-4 ----------
__global__ __launch_bounds__(256) void gather_kernel(
    const int* __restrict__ rowptr, const int* __restrict__ col,
    const unsigned short* __restrict__ h,      // [M][128] bf16
    const float* __restrict__ invd,
    unsigned short* __restrict__ axc,          // [M][128] bf16 (agg*invd)
    int n_nodes) {
    int tid = blockIdx.x * blockDim.x + threadIdx.x;
    int n = tid >> 4;
    if (n >= n_nodes) return;
    int c = (tid & 15) << 3;
    int beg = rowptr[n], end = rowptr[n + 1];
    float a0 = 0.f, a1 = 0.f, a2 = 0.f, a3 = 0.f;
    float a4 = 0.f, a5 = 0.f, a6 = 0.f, a7 = 0.f;
    int i = beg;
    for (; i + 3 < end; i += 4) {
        int s0 = col[i], s1 = col[i + 1], s2 = col[i + 2], s3 = col[i + 3];
        uint4 u0 = *(const uint4*)(h + (size_t)s0 * 128 + c);
        uint4 u1 = *(const uint4*)(h + (size_t)s1 * 128 + c);
        uint4 u2 = *(const uint4*)(h + (size_t)s2 * 128 + c);
        uint4 u3 = *(const uint4*)(h + (size_t)s3 * 128 + c);
        a0 += (bf_lo(u0.x) + bf_lo(u1.x)) + (bf_lo(u2.x) + bf_lo(u3.x));
        a1 += (bf_hi(u0.x) + bf_hi(u1.x)) + (bf_hi(u2.x) + bf_hi(u3.x));
        a2 += (bf_lo(u0.y) + bf_lo(u1.y)) + (bf_lo(u2.y) + bf_lo(u3.y));
        a3 += (bf_hi(u0.y) + bf_hi(u1.y)) + (bf_hi(u2.y) + bf_hi(u3.y));
        a4 += (bf_lo(u0.z) + bf_lo(u1.z)) + (bf_lo(u2.z) + bf_lo(u3.z));
        a5 += (bf_hi(u0.z) + bf_hi(u1.z)) + (bf_hi(u2.z) + bf_hi(u3.z));
        a6 += (bf_lo(u0.w) + bf_lo(u1.w)) + (bf_lo(u2.w) + bf_lo(u3.w));
        a7 += (bf_hi(u0.w) + bf_hi(u1.w)) + (bf_hi(u2.w) + bf_hi(u3.w));
    }
    for (; i < end; i++) {
        uint4 u = *(const uint4*)(h + (size_t)col[i] * 128 + c);
        a0 += bf_lo(u.x); a1 += bf_hi(u.x);
        a2 += bf_lo(u.y); a3 += bf_hi(u.y);
        a4 += bf_lo(u.z); a5 += bf_hi(u.z);
        a6 += bf_lo(u.w); a7 += bf_hi(u.w);
    }
    float s = invd[n];
    uint4 p = {pack_bf(a0 * s, a1 * s), pack_bf(a2 * s, a3 * s),
               pack_bf(a4 * s, a5 * s), pack_bf(a6 * s, a7 * s)};
    *(uint4*)(axc + (size_t)n * 128 + c) = p;
}

// ---------- L3 tail: out = invd*gather(tu[:,0:64]) + tu[:,64:128] + b3 ----------
__global__ __launch_bounds__(256) void gather_add_kernel(
    const int* __restrict__ rowptr, const int* __restrict__ col,
    const unsigned short* __restrict__ tu,     // [M][128] bf16: [t | u]
    const float* __restrict__ invd, const float* __restrict__ b3,
    float* __restrict__ out, int n_nodes) {
    int tid = blockIdx.x * blockDim.x + threadIdx.x;
    int n = tid >> 3;
    if (n >= n_nodes) return;
    int c = (tid & 7) << 3;                    // 8 bf16 of the 64-wide t
    int beg = rowptr[n], end = rowptr[n + 1];
    float a0 = 0.f, a1 = 0.f, a2 = 0.f, a3 = 0.f;
    float a4 = 0.f, a5 = 0.f, a6 = 0.f, a7 = 0.f;
    int i = beg;
    for (; i + 3 < end; i += 4) {
        int s0 = col[i], s1 = col[i + 1], s2 = col[i + 2], s3 = col[i + 3];
        uint4 u0 = *(const uint4*)(tu + (size_t)s0 * 128 + c);
        uint4 u1 = *(const uint4*)(tu + (size_t)s1 * 128 + c);
        uint4 u2 = *(const uint4*)(tu + (size_t)s2 * 128 + c);
        uint4 u3 = *(const uint4*)(tu + (size_t)s3 * 128 + c);
        a0 += (bf_lo(u0.x) + bf_lo(u1.x)) + (bf_lo(u2.x) + bf_lo(u3.x));
        a1 += (bf_hi(u0.x) + bf_hi(u1.x)) + (bf_hi(u2.x) + bf_hi(u3.x));
        a2 += (bf_lo(u0.y) + bf_lo(u1.y)) + (bf_lo(u2.y) + bf_lo(u3.y));
        a3 += (bf_hi(u0.y) + bf_hi(u1.y)) + (bf_hi(u2.y) + bf_hi(u3.y));
        a4 += (bf_lo(u0.z) + bf_lo(u1.z)) + (bf_lo(u2.z) + bf_lo(u3.z));
        a5 += (bf_hi(u0.z) + bf_hi(u1.z)) + (bf_hi(u2.z) + bf_hi(u3.z));
        a6 += (bf_lo(u0.w) + bf_lo(u1.w)) + (bf_lo(u2.w) + bf_lo(u3.w));
        a7 += (bf_hi(u0.w) + bf_hi(u1.w)) + (bf_hi(u2.w) + bf_hi(u3.w));
    }
    for (; i < end; i++) {
        uint4 u = *(const uint4*)(tu + (size_t)col[i] * 128 + c);
        a0 += bf_lo(u.x); a1 += bf_hi(u.x);
        a2 += bf_lo(u.y); a3 += bf_hi(u.y);
        a4 += bf_lo(u.z); a5 += bf_hi(u.z);
        a6 += bf_lo(u.w); a7 += bf_hi(u.w);
    }
    float s = invd[n];
    uint4 uu = *(const uint4*)(tu + (size_t)n * 128 + 64 + c);
    float4 bA = *(const float4*)(b3 + c);
    float4 bB = *(const float4*)(b3 + c + 4);
    float* o = out + (size_t)n * 64 + c;
    o[0] = a0 * s + bf_lo(uu.x) + bA.x;
    o[1] = a1 * s + bf_hi(uu.x) + bA.y;
    o[2] = a2 * s + bf_lo(uu.y) + bA.z;
    o[3] = a3 * s + bf_hi(uu.y) + bA.w;
    o[4] = a4 * s + bf_lo(uu.z) + bB.x;
    o[5] = a5 * s + bf_hi(uu.z) + bB.y;
    o[6] = a6 * s + bf_lo(uu.w) + bB.z;
    o[7] = a7 * s + bf_hi(uu.w) + bB.w;
}

// ---------- MFMA GEMM, double-buffered A slabs ----------
// out[M][N] = [A0half | A1half] @ B[N][NKS*64]^T (+bias) (+relu)
// K halves: ks < NKS/2 reads A0 + ks*64; else A1 + (ks-NKS/2)*64 (row stride 128).
template <int NKS, bool RELU, bool BIAS, typename OUT_T>
__global__ __launch_bounds__(256) void mfma_gemm(
    const unsigned short* __restrict__ A0, const unsigned short* __restrict__ A1,
    const unsigned short* __restrict__ B,       // [N][NKS*64]
    const float* __restrict__ bias,
    OUT_T* __restrict__ out, int M, int N, int nTilesN) {
    constexpr int KTOT = NKS * 64;
    constexpr int LDB = KTOT + 8;
    __shared__ unsigned short As[2][128 * 72];
    __shared__ unsigned short Bs[64 * LDB];
    const int t = threadIdx.x;
    const int w = t >> 6, l = t & 63;
    const int tileM = blockIdx.x / nTilesN;
    const int n0 = (blockIdx.x - tileM * nTilesN) * 64;
    const int m0 = tileM * 128;
    const int lr = l & 15, lq = l >> 4;

    // stage B slab [64][KTOT]
    for (int c = t; c < 64 * (KTOT / 8); c += 256) {
        int row = c / (KTOT / 8);
        int ko = (c - row * (KTOT / 8)) * 8;
        *(uint4*)(&Bs[row * LDB + ko]) =
            *(const uint4*)(&B[(size_t)(n0 + row) * KTOT + ko]);
    }
    // stage A slab 0
    for (int c = t; c < 1024; c += 256) {
        int row = c >> 3;
        int ko = (c & 7) * 8;
        int gm = m0 + row;
        uint4 v = {0u, 0u, 0u, 0u};
        if (gm < M) v = *(const uint4*)(A0 + (size_t)gm * 128 + ko);
        *(uint4*)(&As[0][row * 72 + ko]) = v;
    }
    __syncthreads();

    f32x4 zero = {0.f, 0.f, 0.f, 0.f};
    f32x4 acc[2][4];
#pragma unroll
    for (int tm = 0; tm < 2; tm++)
#pragma unroll
        for (int tn = 0; tn < 4; tn++) acc[tm][tn] = zero;

#pragma unroll
    for (int ks = 0; ks < NKS; ks++) {
        // prefetch next slab into registers
        uint4 pf[4];
        if (ks + 1 < NKS) {
            int ns = ks + 1;
            const unsigned short* Asrc = (ns < NKS / 2)
                ? (A0 + (size_t)ns * 64) : (A1 + (size_t)(ns - NKS / 2) * 64);
#pragma unroll
            for (int j = 0; j < 4; j++) {
                int c = t + j * 256;
                int row = c >> 3;
                int ko = (c & 7) * 8;
                int gm = m0 + row;
                pf[j] = uint4{0u, 0u, 0u, 0u};
                if (gm < M) pf[j] = *(const uint4*)(Asrc + (size_t)gm * 128 + ko);
            }
        }
        // MFMA on current slab
        const unsigned short* as = As[ks & 1];
#pragma unroll
        for (int kc = 0; kc < 2; kc++) {
            int lk = kc * 32 + lq * 8;
            bf16x8 af[2], bfr[4];
            af[0] = *(const bf16x8*)(&as[(w * 32 + lr) * 72 + lk]);
            af[1] = *(const bf16x8*)(&as[(w * 32 + 16 + lr) * 72 + lk]);
#pragma unroll
            for (int tn = 0; tn < 4; tn++)
                bfr[tn] = *(const bf16x8*)(&Bs[(tn * 16 + lr) * LDB + ks * 64 + lk]);
#pragma unroll
            for (int tm = 0; tm < 2; tm++)
#pragma unroll
                for (int tn = 0; tn < 4; tn++)
                    acc[tm][tn] = __builtin_amdgcn_mfma_f32_16x16x32_bf16(
                        af[tm], bfr[tn], acc[tm][tn], 0, 0, 0);
        }
        // publish next slab
        if (ks + 1 < NKS) {
#pragma unroll
            for (int j = 0; j < 4; j++) {
                int c = t + j * 256;
                int row = c >> 3;
                int ko = (c & 7) * 8;
                *(uint4*)(&As[(ks + 1) & 1][row * 72 + ko]) = pf[j];
            }
        }
        __syncthreads();
    }

    // epilogue: C/D layout col = lane&15, row = (lane>>4)*4 + reg  [m89/m91]
#pragma unroll
    for (int tn = 0; tn < 4; tn++) {
        int n = n0 + tn * 16 + lr;
        float bj = BIAS ? bias[n] : 0.f;
#pragma unroll
        for (int tm = 0; tm < 2; tm++) {
#pragma unroll
            for (int i = 0; i < 4; i++) {
                int m = m0 + w * 32 + tm * 16 + lq * 4 + i;
                if (m < M) {
                    float v = acc[tm][tn][i] + bj;
                    if (RELU) v = fmaxf(v, 0.f);
                    stv(&out[(size_t)m * N + n], v);
                }
            }
        }
    }
}

extern "C" void kernel_launch(void* const* d_in, const int* in_sizes, int n_in,
                              void* d_out, int out_size, void* d_ws, size_t ws_size,
                              hipStream_t stream) {
    const float* x  = (const float*)d_in[0];
    const int* ei   = (const int*)d_in[1];
    const float* w1n = (const float*)d_in[2];
    const float* w1r = (const float*)d_in[3];
    const float* b1  = (const float*)d_in[4];
    const float* w2n = (const float*)d_in[5];
    const float* w2r = (const float*)d_in[6];
    const float* b2  = (const float*)d_in[7];
    const float* w3n = (const float*)d_in[8];
    const float* w3r = (const float*)d_in[9];
    const float* b3  = (const float*)d_in[10];
    float* out = (float*)d_out;

    const int E = in_sizes[1] / 2;
    const int* src = ei;
    const int* dst = ei + E;

    // workspace layout (16B-aligned)
    char* ws = (char*)d_ws;
    unsigned short* xb  = (unsigned short*)(ws);               // 12.8 MB [M][128]
    unsigned short* axc = (unsigned short*)(ws + 12800000);    // 12.8 MB (also tu)
    unsigned short* h1b = (unsigned short*)(ws + 25600000);    // 12.8 MB
    unsigned short* h2b = (unsigned short*)(ws + 38400000);    // 12.8 MB
    float* invd         = (float*)(ws + 51200000);             // 200 KB
    int* cnt            = (int*)  (ws + 51404800);             // 200 KB
    int* rowptr         = (int*)  (ws + 51609600);             // 200 KB + 4
    int* cursor         = (int*)  (ws + 51814400);             // 200 KB
    int* col            = (int*)  (ws + 52019200);             // 2.4 MB
    unsigned short* wB1 = (unsigned short*)(ws + 54419200);    // 64 KB [128][256]
    unsigned short* wB2 = (unsigned short*)(ws + 54484736);    // 64 KB
    unsigned short* wB3 = (unsigned short*)(ws + 54550272);    // 32 KB [128][128]
    int* bsum           = (int*)  (ws + 54583040);             // 784 B

    const int nScanBlocks = (NN + 255) / 256;   // 196

    // ---- prep + CSR build ----
    cvt_kernel<<<(NN * 32 + 255) / 256, 256, 0, stream>>>(x, xb, cnt, NN * 32);
    wb3_kernel<<<48, 256, 0, stream>>>(w1n, w1r, w2n, w2r, w3n, w3r, wB1, wB2, wB3);
    count_kernel<<<(E + 255) / 256, 256, 0, stream>>>(dst, cnt, E);
    scan1_kernel<<<nScanBlocks, 256, 0, stream>>>(cnt, rowptr, bsum, NN);
    scan23_kernel<<<nScanBlocks, 256, 0, stream>>>(cnt, rowptr, cursor, invd, bsum,
                                                   nScanBlocks, NN);
    fill_kernel<<<(E + 255) / 256, 256, 0, stream>>>(src, dst, cursor, col, E);

    const int gatherBlocks = NN * 16 / 256;        // 3125
    const int mTiles = (NN + 127) / 128;           // 391

    // layer 1: gather(x) -> axc; h1 = relu([axc|x] @ wB1^T + b1)
    gather_kernel<<<gatherBlocks, 256, 0, stream>>>(rowptr, col, xb, invd, axc, NN);
    mfma_gemm<4, true, true, unsigned short>
        <<<mTiles * 2, 256, 0, stream>>>(axc, xb, wB1, b1, h1b, NN, 128, 2);

    // layer 2
    gather_kernel<<<gatherBlocks, 256, 0, stream>>>(rowptr, col, h1b, invd, axc, NN);
    mfma_gemm<4, true, true, unsigned short>
        <<<mTiles * 2, 256, 0, stream>>>(axc, h1b, wB2, b2, h2b, NN, 128, 2);

    // layer 3 (transform-before-aggregate): tu = h2 @ [w3n;w3r]^T, K=128
    mfma_gemm<2, false, false, unsigned short>
        <<<mTiles * 2, 256, 0, stream>>>(h2b, h2b + 64, wB3, nullptr, axc, NN, 128, 2);
    gather_add_kernel<<<(NN * 8 + 255) / 256, 256, 0, stream>>>(
        rowptr, col, axc, invd, b3, out, NN);
}